// Round 3
// baseline (108.659 us; speedup 1.0000x reference)
//
#include <hip/hip_runtime.h>
#include <math.h>
#include <utility>

#define BB 64
#define NN 512
#define DD 32
#define ZD 34            // DD + 2 (x..., t, y)
#define NE 595           // ZD*(ZD+1)/2 upper-triangular entries
#define WIN 8
#define NW 64            // NN / WIN windows
#define WACT 60          // active windows w = 4..63 (n <= 31 is rank-deficient -> 0)

// fused gram+scan geometry (round-1 layout: entry-per-thread, 128-row segments)
#define SEG 4            // s-segments per batch (128 rows each)
#define RS 128           // rows per segment
#define KWS 16           // windows per segment
#define CH 4             // e-chunks per (b,seg)
#define ECH 149          // entries per chunk (4*149 >= 595)
#define PSTRIDE 17       // 16 exclusive in-segment snapshots + segment total

#define SPW 4            // solve: systems (waves) per workgroup

// entry e -> (i,j), i <= j, row-major upper triangle of ZD x ZD
__device__ inline void ent2ij(int e, int& i, int& j) {
    int ii = 0, rem = e;
    while (rem >= ZD - ii) { rem -= (ZD - ii); ++ii; }
    i = ii; j = ii + rem;
}

// ---- recursive struct-of-scalars: SROA-guaranteed register residency ----
template<int N> struct Pack { Pack<N - 1> head; float v; };
template<> struct Pack<1> { float v; };
template<int I, int N> __device__ __forceinline__ float& pget(Pack<N>& p) {
    static_assert(I < N, "oob");
    if constexpr (I == N - 1) return p.v;
    else return pget<I, N - 1>(p.head);
}

__device__ __forceinline__ float rdlane(float x, int srclane) {
    return __int_as_float(__builtin_amdgcn_readlane(__float_as_int(x), srclane));
}

// Fused window-partial + prefix-scan. Block = (b, s-segment, e-chunk).
// Each thread owns ONE triangle entry e and runs an fp64 prefix chain over the
// segment's 128 rows, emitting the 16 exclusive window snapshots (fp32) plus
// the segment total to P[b][seg][17][NE]. Cross-segment totals are combined in
// dml_solve's staging (<= 3 adds per element). Folds output init: logs[.]=0
// everywhere and means=0 for n < 32.
__global__ __launch_bounds__(256) void dml_gram(const float* __restrict__ xtys,
                                                float* __restrict__ P,
                                                float* __restrict__ out) {
    const int t   = threadIdx.x;
    const int blk = blockIdx.x;                  // ((b*SEG + g)*CH + c)
    const int c   = blk % CH;
    const int bg  = blk / CH;
    const int g   = bg % SEG;
    const int b   = bg / SEG;

    const int gid = blk * 256 + t;
    if (gid < BB * NN) out[BB * NN + gid] = 0.0f;
    if (gid < BB * DD) out[(gid >> 5) * NN + (gid & 31)] = 0.0f;

    __shared__ float zs[RS * ZD];                // 17408 B
    const float* src = xtys + ((size_t)b * NN + (size_t)g * RS) * ZD;
    for (int u = t; u < RS * ZD; u += 256) zs[u] = src[u];
    __syncthreads();

    const int e = c * ECH + t;
    if (t < ECH && e < NE) {
        int i, j;
        ent2ij(e, i, j);
        float* pdst = P + (size_t)(b * SEG + g) * PSTRIDE * NE + e;
        double acc = 0.0;
#pragma unroll
        for (int k = 0; k < KWS; ++k) {
            pdst[k * NE] = (float)acc;           // exclusive: before window k's rows
#pragma unroll
            for (int s8 = 0; s8 < WIN; ++s8) {
                const float* row = &zs[(k * WIN + s8) * ZD];
                acc = fma((double)row[i], (double)row[j], acc);
            }
        }
        pdst[KWS * NE] = (float)acc;             // segment total
    }
}

// ---- solve helpers: lane = COLUMN j of the full symmetric 48x48 bordered
// matrix [[G0, W],[W^T, 0]], W = [x_1..x_8, Xtt0, Xty0]; A[r] = M[r][j].
// Elimination step k: all cross-lane values are wave-uniform (from lane k)
// -> v_readlane (2-cyc VALU, SGPR result), zero LDS/shuffle latency.
// Rows/cols <= k self-neutralize (t = invp*M[k][j] = 0 for eliminated j).
// Rows 42..47 are identically zero for every column -> elimination stops at 42.

template<int R> __device__ __forceinline__
float initval(int j, const float* snL, const float* zb) {
    if constexpr (R < DD) {
        float v = 0.0f;
        if (j < DD) {
            int i0 = (R < j) ? R : j;
            int j0 = (R < j) ? j : R;
            v = snL[i0 * ZD - (i0 * (i0 - 1)) / 2 + (j0 - i0)];
        } else if (j < DD + WIN) {
            v = zb[(j - DD) * ZD + R];
        } else if (j == 40) {
            v = snL[R * ZD - (R * (R - 1)) / 2 + (DD - R)];       // Xtt0[R]
        } else if (j == 41) {
            v = snL[R * ZD - (R * (R - 1)) / 2 + (DD + 1 - R)];   // Xty0[R]
        }
        return v;
    } else if constexpr (R < DD + WIN) {
        return (j < DD) ? zb[(R - DD) * ZD + j] : 0.0f;
    } else if constexpr (R == 40) {
        return (j < DD) ? snL[j * ZD - (j * (j - 1)) / 2 + (DD - j)] : 0.0f;
    } else if constexpr (R == 41) {
        return (j < DD) ? snL[j * ZD - (j * (j - 1)) / 2 + (DD + 1 - j)] : 0.0f;
    } else {
        return 0.0f;
    }
}
template<int R> __device__ __forceinline__
void init_rec(Pack<48>& A, int j, const float* snL, const float* zb) {
    if constexpr (R < 48) {
        pget<R>(A) = initval<R>(j, snL, zb);
        init_rec<R + 1>(A, j, snL, zb);
    }
}

template<int K, int R> __device__ __forceinline__
void elim_rows(Pack<48>& A, float t) {
    if constexpr (R < DD + 10) {               // rows 42..47 are always zero
        float fr = rdlane(pget<R>(A), K);      // M[R][K], wave-uniform
        pget<R>(A) = fmaf(-fr, t, pget<R>(A));
        elim_rows<K, R + 1>(A, t);
    }
}
template<int K> __device__ __forceinline__
void elim_step(Pack<48>& A) {
    float piv  = rdlane(pget<K>(A), K);        // M[K][K]
    float invp = (piv > 1e-30f) ? 1.0f / piv : 0.0f;
    float t    = invp * pget<K>(A);            // invp * M[K][j]; 0 for done cols
    elim_rows<K, K + 1>(A, t);
}
template<int... Ks> __device__ __forceinline__
void elim_all(Pack<48>& A, std::integer_sequence<int, Ks...>) {
    ((elim_step<Ks>(A)), ...);
}

template<int R> __device__ __forceinline__
void kdump(Pack<48>& A, float* Kl, int c) {    // lanes 32..41: column c of K
    if constexpr (R < DD + 10) {
        Kl[(R - DD) * 10 + c] = -pget<R>(A);
        kdump<R + 1>(A, Kl, c);
    }
}

// ---- per-lane 8x8 GJ (one system per lane, zero cross-lane traffic) ----
template<int L> __device__ __forceinline__
void tinit(Pack<96>& T, int m, const float* Kl, const float* zb) {
    if constexpr (L < 96) {
        constexpr int I = L / 12, J = L % 12;
        float v;
        if constexpr (J < 8) {
            float kij = (I < m && J < m) ? Kl[I * 10 + J] : 0.0f;
            v = kij + ((I == J) ? 1.0f : 0.0f);
        } else if constexpr (J == 8)  v = (I < m) ? Kl[I * 10 + 8] : 0.0f;   // KUp
        else if constexpr (J == 9)    v = (I < m) ? zb[I * ZD + DD] : 0.0f;  // t_i
        else if constexpr (J == 10)   v = (I < m) ? Kl[I * 10 + 9] : 0.0f;   // KUq
        else                          v = (I < m) ? zb[I * ZD + DD + 1] : 0.0f; // y_i
        pget<L>(T) = v;
        tinit<L + 1>(T, m, Kl, zb);
    }
}
template<int K, int I, int J> __device__ __forceinline__
void gj_cols(Pack<96>& T, float f) {
    if constexpr (J < 12) {
        pget<I * 12 + J>(T) = fmaf(-f, pget<K * 12 + J>(T), pget<I * 12 + J>(T));
        gj_cols<K, I, J + 1>(T, f);
    }
}
template<int K, int I> __device__ __forceinline__
void gj_rows(Pack<96>& T, float invp) {
    if constexpr (I < 8) {
        if constexpr (I != K) {
            float f = pget<I * 12 + K>(T) * invp;
            gj_cols<K, I, K + 1>(T, f);
        }
        gj_rows<K, I + 1>(T, invp);
    }
}
template<int K> __device__ __forceinline__
void gj_step(Pack<96>& T) {
    float piv  = pget<K * 12 + K>(T);
    float invp = (piv > 1e-30f || piv < -1e-30f) ? 1.0f / piv : 0.0f;
    gj_rows<K, 0>(T, invp);
}
template<int... Ks> __device__ __forceinline__
void gj_all(Pack<96>& T, std::integer_sequence<int, Ks...>) {
    ((gj_step<Ks>(T)), ...);
}
template<int I> __device__ __forceinline__
void finacc(Pack<96>& T, int m, const float* Kl, const float* zb,
            double& dt, double& nt) {
    if constexpr (I < 8) {
        if (I < m) {
            float di   = pget<I * 12 + I>(T);
            float dinv = (di > 1e-30f || di < -1e-30f) ? 1.0f / di : 0.0f;
            double s1 = (double)(pget<I * 12 + 8>(T) * dinv);
            double s2 = (double)(pget<I * 12 + 9>(T) * dinv);
            double r1 = (double)(pget<I * 12 + 10>(T) * dinv);
            double r2 = (double)(pget<I * 12 + 11>(T) * dinv);
            double g  = (double)Kl[80 + I] - (double)zb[I * ZD + DD]; // KpU_i - t_i
            dt += g * (s1 - s2);
            nt += g * (r1 - r2);
        }
        finacc<I + 1>(T, m, Kl, zb, dt, nt);
    }
}

// FOUR systems per 256-thread workgroup: wave wid owns system
// id = blockIdx.x*4 + wid = (b, w>=4), with private LDS slices. Packing 4
// 1-wave systems per WG lifts the per-CU workgroup-slot occupancy cap
// (observed 24% with 64-thread WGs). Snapshot Sn[w] is assembled during LDS
// staging: Sn[w] = piece[g][k] + sum_{g'<g} total[g'], g=w>>4, k=w&15.
// Then readlane-based column elimination, and one 8x8 GJ PER LANE (lanes 0..7).
//   den = Stt0 - Kpp + sum_i (KpU_i - t_i)(s1_i - s2_i), s1=S^-1 KUp, s2=S^-1 t
//   num = Sty0 - Kpq + sum_i (KpU_i - t_i)(r1_i - r2_i), r1=S^-1 KUq, r2=S^-1 y
__global__ __launch_bounds__(256) void dml_solve(const float* __restrict__ xtys,
                                                 const float* __restrict__ P,
                                                 float* __restrict__ out) {
    const int wid  = threadIdx.x >> 6;
    const int lane = threadIdx.x & 63;
    const int id   = blockIdx.x * SPW + wid;   // 0 .. BB*WACT-1
    const int w    = (id % WACT) + 4;
    const int b    = id / WACT;
    const int g    = w >> 4;
    const int k    = w & 15;

    __shared__ float snL[SPW][NE];
    __shared__ float zb[SPW][WIN * ZD];
    __shared__ float Kl[SPW][100];       // K = W^T G0^-1 W (10x10)
    float* snW = snL[wid];
    float* zbW = zb[wid];
    float* KlW = Kl[wid];

    const float* pb  = P + (size_t)b * SEG * PSTRIDE * NE;
    const float* src = xtys + ((size_t)b * NN + (size_t)w * WIN) * ZD;
    for (int u = lane; u < NE; u += 64) {
        float v = pb[(size_t)(g * PSTRIDE + k) * NE + u];
        for (int g2 = 0; g2 < g; ++g2)
            v += pb[(size_t)(g2 * PSTRIDE + KWS) * NE + u];
        snW[u] = v;
    }
    for (int u = lane; u < WIN * ZD; u += 64) zbW[u] = src[u];
    __syncthreads();

    Pack<48> A;
    init_rec<0>(A, lane, snW, zbW);      // lanes >= 42 (incl. 48..63) get zeros

    elim_all(A, std::make_integer_sequence<int, DD>{});

    if (lane >= DD && lane < DD + 10) kdump<DD>(A, KlW, lane - DD);
    __syncthreads();

    if (lane < 8) {
        const int m = lane + 1;          // system l = lane: n = 8w + lane
        Pack<96> T;
        tinit<0>(T, m, KlW, zbW);
        gj_all(T, std::make_integer_sequence<int, 8>{});
        double dt = 0.0, nt = 0.0;
        finacc<0>(T, m, KlW, zbW, dt, nt);
        double Stt0 = (double)snW[592];
        double Sty0 = (double)snW[593];
        double den  = Stt0 - (double)KlW[88] + dt;  // Stt0 - Kpp + dterm
        double num  = Sty0 - (double)KlW[89] + nt;  // Sty0 - Kpq + nterm
        double val  = (den > 0.0) ? num / den : 0.0;
        if (!isfinite(val)) val = 0.0;
        out[b * NN + w * WIN + lane] = (float)val;
    }
}

extern "C" void kernel_launch(void* const* d_in, const int* in_sizes, int n_in,
                              void* d_out, int out_size, void* d_ws, size_t ws_size,
                              hipStream_t stream) {
    const float* xtys = (const float*)d_in[0];
    float* out = (float*)d_out;
    float* P = (float*)d_ws;   // [BB][SEG][17][NE] fp32 = 10.36 MB

    hipLaunchKernelGGL(dml_gram, dim3(BB * SEG * CH), dim3(256), 0, stream, xtys, P, out);
    hipLaunchKernelGGL(dml_solve, dim3(BB * WACT / SPW), dim3(256), 0, stream, xtys, P, out);
}

// Round 4
// 98.085 us; speedup vs baseline: 1.1078x; 1.1078x over previous
//
#include <hip/hip_runtime.h>
#include <math.h>
#include <utility>

#define BB 64
#define NN 512
#define DD 32
#define ZD 34            // DD + 2 (x..., t, y)
#define NE 595           // ZD*(ZD+1)/2 upper-triangular entries
#define WIN 8
#define NW 64            // NN / WIN windows
#define WACT 60          // active windows w = 4..63 (n <= 31 is rank-deficient -> 0)

// fused gram+scan geometry (entry-per-thread, 128-row segments)
#define SEG 4            // s-segments per batch (128 rows each)
#define RS 128           // rows per segment
#define KWS 16           // windows per segment
#define CH 4             // e-chunks per (b,seg)
#define ECH 149          // entries per chunk (4*149 >= 595)
#define PSTRIDE 17       // 16 exclusive in-segment snapshots + segment total

#define SPW 4            // solve: systems (waves) per workgroup

// entry e -> (i,j), i <= j, row-major upper triangle of ZD x ZD
__device__ inline void ent2ij(int e, int& i, int& j) {
    int ii = 0, rem = e;
    while (rem >= ZD - ii) { rem -= (ZD - ii); ++ii; }
    i = ii; j = ii + rem;
}

// ---- recursive struct-of-scalars: SROA-guaranteed register residency ----
template<int N> struct Pack { Pack<N - 1> head; float v; };
template<> struct Pack<1> { float v; };
template<int I, int N> __device__ __forceinline__ float& pget(Pack<N>& p) {
    static_assert(I < N, "oob");
    if constexpr (I == N - 1) return p.v;
    else return pget<I, N - 1>(p.head);
}

__device__ __forceinline__ float rdlane(float x, int srclane) {
    return __int_as_float(__builtin_amdgcn_readlane(__float_as_int(x), srclane));
}
__device__ __forceinline__ float bperm(int byteaddr, float x) {
    return __int_as_float(__builtin_amdgcn_ds_bpermute(byteaddr, __float_as_int(x)));
}

// Fused window-partial + prefix-scan. Block = (b, s-segment, e-chunk).
// Each thread owns ONE triangle entry e and runs an fp64 prefix chain over the
// segment's 128 rows, emitting the 16 exclusive window snapshots (fp32) plus
// the segment total to P[b][seg][17][NE]. Cross-segment totals are combined in
// dml_solve's staging (<= 3 adds per element). Folds output init: logs[.]=0
// everywhere and means=0 for n < 32.
__global__ __launch_bounds__(256) void dml_gram(const float* __restrict__ xtys,
                                                float* __restrict__ P,
                                                float* __restrict__ out) {
    const int t   = threadIdx.x;
    const int blk = blockIdx.x;                  // ((b*SEG + g)*CH + c)
    const int c   = blk % CH;
    const int bg  = blk / CH;
    const int g   = bg % SEG;
    const int b   = bg / SEG;

    const int gid = blk * 256 + t;
    if (gid < BB * NN) out[BB * NN + gid] = 0.0f;
    if (gid < BB * DD) out[(gid >> 5) * NN + (gid & 31)] = 0.0f;

    __shared__ float zs[RS * ZD];                // 17408 B
    const float* src = xtys + ((size_t)b * NN + (size_t)g * RS) * ZD;
    for (int u = t; u < RS * ZD; u += 256) zs[u] = src[u];
    __syncthreads();

    const int e = c * ECH + t;
    if (t < ECH && e < NE) {
        int i, j;
        ent2ij(e, i, j);
        float* pdst = P + (size_t)(b * SEG + g) * PSTRIDE * NE + e;
        double acc = 0.0;
#pragma unroll
        for (int k = 0; k < KWS; ++k) {
            pdst[k * NE] = (float)acc;           // exclusive: before window k's rows
#pragma unroll
            for (int s8 = 0; s8 < WIN; ++s8) {
                const float* row = &zs[(k * WIN + s8) * ZD];
                acc = fma((double)row[i], (double)row[j], acc);
            }
        }
        pdst[KWS * NE] = (float)acc;             // segment total
    }
}

// ---- solve helpers: lane = COLUMN j of the full symmetric 48x48 bordered
// matrix [[G0, W],[W^T, 0]], W = [x_1..x_8, Xtt0, Xty0]; A[r] = M[r][j].
// Strength-reduced indices: e(i0,j0) = (R<j) ? CR_R + j : off_j + R with
// CR_R = R*ZD - R(R-1)/2 - R compile-time and off_j per-lane.

template<int R> __device__ __forceinline__
float initval(int j, int off_j, int zoff, const float* snL, const float* zb) {
    constexpr int RC = (R < DD) ? (R * ZD - (R * (R - 1)) / 2 - R) : 0;
    if constexpr (R < DD) {
        float v = 0.0f;
        if (j < DD) {
            int idx = (R < j) ? (RC + j) : (off_j + R);
            v = snL[idx];
        } else if (j < DD + WIN) {
            v = zb[zoff + R];
        } else if (j == 40) {
            v = snL[RC + DD];                    // Xtt0[R]
        } else if (j == 41) {
            v = snL[RC + DD + 1];                // Xty0[R]
        }
        return v;
    } else if constexpr (R < DD + WIN) {
        return (j < DD) ? zb[(R - DD) * ZD + j] : 0.0f;
    } else if constexpr (R == 40) {
        return (j < DD) ? snL[off_j + DD] : 0.0f;
    } else if constexpr (R == 41) {
        return (j < DD) ? snL[off_j + DD + 1] : 0.0f;
    } else {
        return 0.0f;
    }
}
template<int R> __device__ __forceinline__
void init_rec(Pack<48>& A, int j, int off_j, int zoff,
              const float* snL, const float* zb) {
    if constexpr (R < 48) {
        pget<R>(A) = initval<R>(j, off_j, zoff, snL, zb);
        init_rec<R + 1>(A, j, off_j, zoff, snL, zb);
    }
}

template<int K, int R> __device__ __forceinline__
void elim_rows(Pack<48>& A, float t) {
    if constexpr (R < DD + 10) {               // rows 42..47 are always zero
        float fr = rdlane(pget<R>(A), K);      // M[R][K], wave-uniform
        pget<R>(A) = fmaf(-fr, t, pget<R>(A));
        elim_rows<K, R + 1>(A, t);
    }
}
template<int K> __device__ __forceinline__
void elim_step(Pack<48>& A) {
    float piv  = rdlane(pget<K>(A), K);        // M[K][K]
    float invp = (piv > 1e-30f) ? 1.0f / piv : 0.0f;
    float t    = invp * pget<K>(A);            // invp * M[K][j]; 0 for done cols
    elim_rows<K, K + 1>(A, t);
}
template<int... Ks> __device__ __forceinline__
void elim_all(Pack<48>& A, std::integer_sequence<int, Ks...>) {
    ((elim_step<Ks>(A)), ...);
}

template<int R> __device__ __forceinline__
void kdump(Pack<48>& A, float* Kl, int c) {    // lanes 32..41: column c of K
    if constexpr (R < DD + 10) {
        Kl[(R - DD) * 10 + c] = -pget<R>(A);
        kdump<R + 1>(A, Kl, c);
    }
}

// ---- row-parallel 8x8 GJ: lane = (sys, row) = (lane>>3, lane&7). Each lane
// holds ONE row (12 floats) of its system's tableau in registers. Pivot-row
// broadcast via ds_bpermute within the 8-lane group. Operation-for-operation
// identical arithmetic to the per-lane version: inactive rows (row >= m) are
// identity rows with zero RHS -> f = 0 forever, contribute exactly 0.
template<int L> __device__ __forceinline__
void tinit(Pack<12>& T, int row, int sys, const float* Kl, const float* zb) {
    if constexpr (L < 12) {
        float v;
        if constexpr (L < 8) {
            float kij = (row <= sys && L <= sys) ? Kl[row * 10 + L] : 0.0f;
            v = kij + ((row == L) ? 1.0f : 0.0f);
        } else if constexpr (L == 8)  v = (row <= sys) ? Kl[row * 10 + 8] : 0.0f;       // KUp
        else if constexpr (L == 9)    v = (row <= sys) ? zb[row * ZD + DD] : 0.0f;      // t_i
        else if constexpr (L == 10)   v = (row <= sys) ? Kl[row * 10 + 9] : 0.0f;       // KUq
        else                          v = (row <= sys) ? zb[row * ZD + DD + 1] : 0.0f;  // y_i
        pget<L>(T) = v;
        tinit<L + 1>(T, row, sys, Kl, zb);
    }
}
template<int K, int J> __device__ __forceinline__
void gjp_cols(Pack<12>& T, float f, int pb) {
    if constexpr (J < 12) {
        float pk = bperm(pb + 4 * K, pget<J>(T));   // pivot row K, col J
        pget<J>(T) = fmaf(-f, pk, pget<J>(T));
        gjp_cols<K, J + 1>(T, f, pb);
    }
}
template<int K> __device__ __forceinline__
void gjp_step(Pack<12>& T, int pb, int row, float& diag) {
    float pkK  = bperm(pb + 4 * K, pget<K>(T));     // M[K][K] of own system
    float invp = (pkK > 1e-30f || pkK < -1e-30f) ? 1.0f / pkK : 0.0f;
    float f    = (row == K) ? 0.0f : pget<K>(T) * invp;
    gjp_cols<K, K + 1>(T, f, pb);
    if (row == K) diag = pget<K>(T);                // T[K][K] final after step K
}
template<int... Ks> __device__ __forceinline__
void gjp_all(Pack<12>& T, int pb, int row, float& diag,
             std::integer_sequence<int, Ks...>) {
    ((gjp_step<Ks>(T, pb, row, diag)), ...);
}

// FOUR systems per 256-thread workgroup: wave wid owns system
// id = blockIdx.x*4 + wid = (b, w>=4), with private per-wave LDS slices (no
// __syncthreads needed: DS pipe is in-order per wave, slices are not shared).
// Snapshot Sn[w] = piece[g][k] + sum_{g'<g} total[g'], g=w>>4, k=w&15.
// Readlane-based column elimination -> K = W^T G0^-1 W (10x10), then
// row-parallel GJ across all 64 lanes (8 systems x 8 rows).
//   den = Stt0 - Kpp + sum_i (KpU_i - t_i)(s1_i - s2_i), s1=S^-1 KUp, s2=S^-1 t
//   num = Sty0 - Kpq + sum_i (KpU_i - t_i)(r1_i - r2_i), r1=S^-1 KUq, r2=S^-1 y
__global__ __launch_bounds__(256) void dml_solve(const float* __restrict__ xtys,
                                                 const float* __restrict__ P,
                                                 float* __restrict__ out) {
    const int wid  = threadIdx.x >> 6;
    const int lane = threadIdx.x & 63;
    const int id   = blockIdx.x * SPW + wid;   // 0 .. BB*WACT-1
    const int w    = (id % WACT) + 4;
    const int b    = id / WACT;
    const int g    = w >> 4;
    const int k    = w & 15;

    __shared__ float snL[SPW][NE];
    __shared__ float zb[SPW][WIN * ZD];
    __shared__ float Kl[SPW][100];       // K = W^T G0^-1 W (10x10)
    float* snW = snL[wid];
    float* zbW = zb[wid];
    float* KlW = Kl[wid];

    const float* pb_  = P + (size_t)b * SEG * PSTRIDE * NE;
    const float* src  = xtys + ((size_t)b * NN + (size_t)w * WIN) * ZD;
    for (int u = lane; u < NE; u += 64) {
        float v = pb_[(size_t)(g * PSTRIDE + k) * NE + u];
        for (int g2 = 0; g2 < g; ++g2)
            v += pb_[(size_t)(g2 * PSTRIDE + KWS) * NE + u];
        snW[u] = v;
    }
    for (int u = lane; u < WIN * ZD; u += 64) zbW[u] = src[u];
    // no __syncthreads: same-wave LDS producer/consumer, DS pipe is in-order

    const int j     = lane;
    const int off_j = j * (ZD - 1) - (j * (j - 1)) / 2;   // j*ZD - j(j-1)/2 - j
    const int zoff  = (j - DD) * ZD;

    Pack<48> A;
    init_rec<0>(A, j, off_j, zoff, snW, zbW);  // lanes >= 42 get zeros

    elim_all(A, std::make_integer_sequence<int, DD>{});

    if (lane >= DD && lane < DD + 10) kdump<DD>(A, KlW, lane - DD);
    // no __syncthreads: kdump (DS writes) -> tinit (DS reads) same wave, in-order

    const int sys = lane >> 3;           // system index: n = 8w + sys
    const int row = lane & 7;
    const int pb  = (threadIdx.x & ~7) << 2;   // byte addr base of own group's rows

    Pack<12> T;
    tinit<0>(T, row, sys, KlW, zbW);
    float diag = 1.0f;
    gjp_all(T, pb, row, diag, std::make_integer_sequence<int, 8>{});

    // per-row contribution; inactive rows (row > sys) have zero RHS -> 0
    float dinv = (diag > 1e-30f || diag < -1e-30f) ? 1.0f / diag : 0.0f;
    double s1 = (double)(pget<8>(T) * dinv);
    double s2 = (double)(pget<9>(T) * dinv);
    double r1 = (double)(pget<10>(T) * dinv);
    double r2 = (double)(pget<11>(T) * dinv);
    double gg = (double)KlW[80 + row] - (double)zbW[row * ZD + DD]; // KpU_i - t_i
    double cd = gg * (s1 - s2);
    double cn = gg * (r1 - r2);
#pragma unroll
    for (int m = 1; m < 8; m <<= 1) {
        cd += __shfl_xor(cd, m, 8);
        cn += __shfl_xor(cn, m, 8);
    }

    double Stt0 = (double)snW[592];
    double Sty0 = (double)snW[593];
    double den  = Stt0 - (double)KlW[88] + cd;  // Stt0 - Kpp + dterm
    double num  = Sty0 - (double)KlW[89] + cn;  // Sty0 - Kpq + nterm
    double val  = (den > 0.0) ? num / den : 0.0;
    if (!isfinite(val)) val = 0.0;
    if (row == 0) out[b * NN + w * WIN + sys] = (float)val;
}

extern "C" void kernel_launch(void* const* d_in, const int* in_sizes, int n_in,
                              void* d_out, int out_size, void* d_ws, size_t ws_size,
                              hipStream_t stream) {
    const float* xtys = (const float*)d_in[0];
    float* out = (float*)d_out;
    float* P = (float*)d_ws;   // [BB][SEG][17][NE] fp32 = 10.36 MB

    hipLaunchKernelGGL(dml_gram, dim3(BB * SEG * CH), dim3(256), 0, stream, xtys, P, out);
    hipLaunchKernelGGL(dml_solve, dim3(BB * WACT / SPW), dim3(256), 0, stream, xtys, P, out);
}